// Round 1
// 308.044 us; speedup vs baseline: 1.3917x; 1.3917x over previous
//
#include <hip/hip_runtime.h>

// Constants: M=5,N=2 -> U=3, GROUPS=4, DIL=2, KSIZE=13; B=8, C=O=256, T=16384,
// Ti=8192, BOUNDARY=sqrt(2). Folded form: t0/d2/d1 are each 5-tap convs over
// xs_i[c,m]=x[b,c,2m+i]:
//   t0[t] = mask * (sum_e w0[e]*xs[t-2+e] + bias)        w0[e]=w[.,.,3e]
//   d2[t] = mask * sum_e (w1[e-1]-w1[e])*xs[t-2+e]       w1[j]=w[.,.,3j+1]
//   d1[t] = mask * sum_e (w2[e-1]-w2[e])*xs[t-2+e]       w2[j]=w[.,.,3j+2]
//   den   = clip(t0 - mean5(t0), 1, sqrt(2))
//   out[2t+i] = 0.25*(t0 + (d1+d2)/den + 2*(d2-d1)/den^2),  mask: 2<=t<=8189
//
// R1: TB 128->64 to cut LDS 117.7KB->64KB => 2 blocks/CU (4 waves/SIMD) for
// cross-block phase overlap (occupancy was the bottleneck: Mfma 10.6%, VALU
// 17%, HBM 14%, occ 23%). Also j-major combine indexing for coalesced stores
// (was 64 rows per store instruction; now 4x 128B half-dense segments).

typedef float v4f __attribute__((ext_vector_type(4)));
typedef short v8s __attribute__((ext_vector_type(8)));

#define TI 8192
#define TFULL 16384
#define TB 64               // stored outputs per phase per block
#define XPH_BYTES 10752     // 84 rows * 128 B (swizzled [t][c] bf16 tile)
#define T0L_F 0             // f32 index of t0l  [80][68]
#define D2L_F 5440          // 80*68
#define D1L_F 10880
#define BIAS_F 16320        // 64 floats
#define LDS_BYTES 65536     // 16320*4 + 256

__device__ __forceinline__ unsigned bf16w(float f) {
    unsigned u = __float_as_uint(f);
    return (u + 0x7FFFu + ((u >> 16) & 1u)) >> 16;
}

// ---------------- prep: fold weights into bf16 A-fragments ----------------
// ws element layout (ushort): ((((g*5+e)*2+kc)*12+mt)*64+lane)*8+j
// holds A[m][k]: m=16*mt+(lane&15) (row: a=m>>6 acc, o=16*(mt&3)+(lane&15)),
// k=32*kc+(lane>>4)*8+j = channel c.
__global__ void prep_kernel(const float* __restrict__ w, unsigned short* __restrict__ gw) {
    int id = blockIdx.x * 256 + threadIdx.x;   // 245760 total
    int j    = id & 7;
    int lane = (id >> 3) & 63;
    int fid  = id >> 9;
    int mt   = fid % 12;  fid /= 12;
    int kc   = fid & 1;   fid >>= 1;
    int e    = fid % 5;
    int g    = fid / 5;
    int a  = mt >> 2;
    int mg = mt & 3;
    int o  = 16 * mg + (lane & 15);
    int c  = 32 * kc + (lane >> 4) * 8 + j;
    const float* wb = w + (((size_t)(g * 64 + o)) * 64 + c) * 13;
    float val;
    if (a == 0) {
        val = wb[3 * e];
    } else {
        int tap = (a == 1) ? 1 : 2;
        float lo = (e > 0) ? wb[3 * (e - 1) + tap] : 0.0f;
        float hi = (e < 4) ? wb[3 * e + tap] : 0.0f;
        val = lo - hi;
    }
    gw[id] = (unsigned short)bf16w(val);
}

// ---------------- main ----------------
__global__ __launch_bounds__(512, 4)
void pconv_mfma(const unsigned short* __restrict__ gw, const float* __restrict__ x,
                const float* __restrict__ bias, float* __restrict__ out) {
    extern __shared__ char smem[];
    float* smemf = (float*)smem;

    const int tid  = threadIdx.x;
    const int lane = tid & 63;
    const int wv   = tid >> 6;      // 0..7
    const int mg   = wv >> 1;       // o-slice [16mg,16mg+16)
    const int ph   = wv & 1;        // dilation phase
    const int col  = lane & 15;
    const int quad = lane >> 4;

    const int tileIdx = blockIdx.x;       // 0..127
    const int g       = blockIdx.y;       // 0..3
    const int b       = blockIdx.z;       // 0..7
    const int tb      = tileIdx * TB;

    // ---- stage bias ----
    if (tid < 64) smemf[BIAS_F + tid] = bias[g * 64 + tid];

    // ---- stage x: de-interleave + transpose + bf16, XOR-swizzled [t][c] ----
    // phase tile p: rows trel in [0,84) <-> m = tb-4+trel; 16B block of 8 ch at
    // byte: p*XPH + trel*128 + ((cblk ^ (trel&7))<<4) + (c&7)*2
    {
        const float* xb = x + ((size_t)(b * 256 + g * 64)) * TFULL;
        const int v0 = 2 * tb - 8;          // 168 values per channel
        for (int f = tid; f < 1344; f += 512) {       // 32 cpairs * 42 vquads
            int q  = f % 42;
            int cp = f / 42;
            int vq = v0 + 4 * q;
            const float* r0 = xb + (size_t)(2 * cp) * TFULL;
            const float* r1 = r0 + TFULL;
            float a0, a1, a2, a3, b0, b1, b2, b3;
            if (vq >= 0 && vq + 3 < TFULL) {
                v4f A4 = *(const v4f*)(r0 + vq);
                v4f B4 = *(const v4f*)(r1 + vq);
                a0 = A4[0]; a1 = A4[1]; a2 = A4[2]; a3 = A4[3];
                b0 = B4[0]; b1 = B4[1]; b2 = B4[2]; b3 = B4[3];
            } else {
                a0 = (vq >= 0 && vq < TFULL) ? r0[vq] : 0.0f;
                a1 = (vq + 1 >= 0 && vq + 1 < TFULL) ? r0[vq + 1] : 0.0f;
                a2 = (vq + 2 >= 0 && vq + 2 < TFULL) ? r0[vq + 2] : 0.0f;
                a3 = (vq + 3 >= 0 && vq + 3 < TFULL) ? r0[vq + 3] : 0.0f;
                b0 = (vq >= 0 && vq < TFULL) ? r1[vq] : 0.0f;
                b1 = (vq + 1 >= 0 && vq + 1 < TFULL) ? r1[vq + 1] : 0.0f;
                b2 = (vq + 2 >= 0 && vq + 2 < TFULL) ? r1[vq + 2] : 0.0f;
                b3 = (vq + 3 >= 0 && vq + 3 < TFULL) ? r1[vq + 3] : 0.0f;
            }
            int cblk = cp >> 2;
            int woff = (cp & 3) * 4;
            unsigned w0 = bf16w(a0) | (bf16w(b0) << 16);  // p=0, trel=2q
            unsigned w1 = bf16w(a1) | (bf16w(b1) << 16);  // p=1, trel=2q
            unsigned w2 = bf16w(a2) | (bf16w(b2) << 16);  // p=0, trel=2q+1
            unsigned w3 = bf16w(a3) | (bf16w(b3) << 16);  // p=1, trel=2q+1
            int t0r = 2 * q, t1r = 2 * q + 1;
            *(unsigned*)(smem + 0 * XPH_BYTES + t0r * 128 + ((cblk ^ (t0r & 7)) << 4) + woff) = w0;
            *(unsigned*)(smem + 1 * XPH_BYTES + t0r * 128 + ((cblk ^ (t0r & 7)) << 4) + woff) = w1;
            *(unsigned*)(smem + 0 * XPH_BYTES + t1r * 128 + ((cblk ^ (t1r & 7)) << 4) + woff) = w2;
            *(unsigned*)(smem + 1 * XPH_BYTES + t1r * 128 + ((cblk ^ (t1r & 7)) << 4) + woff) = w3;
        }
    }
    __syncthreads();

    // ---- K-loop: 10 ksteps (5 taps x 2 kchunks), 15 MFMAs each ----
    const unsigned short* gwp = gw + (size_t)g * 61440;
    v4f acc[3][5];
    #pragma unroll
    for (int a = 0; a < 3; ++a)
        #pragma unroll
        for (int u = 0; u < 5; ++u) acc[a][u] = (v4f){0.f, 0.f, 0.f, 0.f};

    const char* xph = smem + ph * XPH_BYTES;
    #pragma unroll
    for (int e = 0; e < 5; ++e) {
        #pragma unroll
        for (int kc = 0; kc < 2; ++kc) {
            v8s Af[3];
            #pragma unroll
            for (int a = 0; a < 3; ++a)
                Af[a] = *(const v8s*)(gwp + (((e * 2 + kc) * 12 + 4 * a + mg) << 9) + (lane << 3));
            // B addr: xrel = 16u+col+e; block-swizzle sel = (col+e)&7
            const int sw = (col + e) * 128 + (((4 * kc + quad) ^ ((col + e) & 7)) << 4);
            #pragma unroll
            for (int u = 0; u < 5; ++u) {
                v8s Bf = *(const v8s*)(xph + u * 2048 + sw);
                #pragma unroll
                for (int a = 0; a < 3; ++a)
                    acc[a][u] = __builtin_amdgcn_mfma_f32_16x16x32_bf16(Af[a], Bf, acc[a][u], 0, 0, 0);
            }
        }
    }
    __syncthreads();   // GEMM done; safe to alias x tile with epilogue buffers

    // ---- epilogue, phase-serial ----
    const int o0 = 16 * mg + 4 * quad;                 // C/D row base for this lane
    const v4f bias4 = *(const v4f*)(smemf + BIAS_F + o0);
    const size_t outbase = ((size_t)(b * 256 + g * 64)) * TFULL;

    #pragma unroll
    for (int p = 0; p < 2; ++p) {
        if (ph == p) {
            // stage t0/d2/d1 to [idx][o] (stride 68), masked (+bias for t0)
            #pragma unroll
            for (int a = 0; a < 3; ++a) {
                float* dst = smemf + (a == 0 ? T0L_F : (a == 1 ? D2L_F : D1L_F));
                #pragma unroll
                for (int u = 0; u < 5; ++u) {
                    int idx = 16 * u + col;            // t = tb-2+idx
                    int t = tb - 2 + idx;
                    bool valid = (t >= 2) && (t <= TI - 3);
                    v4f v = acc[a][u];
                    if (a == 0) v = v + bias4;
                    if (!valid) v = (v4f){0.f, 0.f, 0.f, 0.f};
                    *(v4f*)(dst + idx * 68 + o0) = v;
                }
            }
        }
        __syncthreads();
        // combine: 1024 (o, jq) items, lanes j-major (coalesced stores,
        // LDS reads 2-way aliased = free)
        #pragma unroll
        for (int it = 0; it < 2; ++it) {
            int f = tid + it * 512;
            int jq = f & 15;
            int o  = f >> 4;                            // 0..63
            float* ob = out + outbase + (size_t)o * TFULL;
            #pragma unroll
            for (int s = 0; s < 4; ++s) {
                int j = jq + 16 * s;                    // output t = tb + j
                float w0 = smemf[T0L_F + (j + 0) * 68 + o];
                float w1 = smemf[T0L_F + (j + 1) * 68 + o];
                float w2 = smemf[T0L_F + (j + 2) * 68 + o];
                float w3 = smemf[T0L_F + (j + 3) * 68 + o];
                float w4 = smemf[T0L_F + (j + 4) * 68 + o];
                float d2v = smemf[D2L_F + (j + 2) * 68 + o];
                float d1v = smemf[D1L_F + (j + 2) * 68 + o];
                float t0 = w2;
                float m5 = 0.2f * (w0 + w1 + w2 + w3 + w4);
                float den = fminf(fmaxf(t0 - m5, 1.0f), 1.41421356237309515f);
                float rc = 1.0f / den;
                float res = 0.25f * (t0 + (d1v + d2v) * rc +
                                     2.0f * (d2v - d1v) * rc * rc);
                ob[2 * (tb + j) + p] = res;
            }
        }
        __syncthreads();
    }
}

extern "C" void kernel_launch(void* const* d_in, const int* in_sizes, int n_in,
                              void* d_out, int out_size, void* d_ws, size_t ws_size,
                              hipStream_t stream) {
    const float* x  = (const float*)d_in[0];  // (8, 256, 16384) f32
    const float* w  = (const float*)d_in[1];  // (256, 64, 13)   f32
    const float* bb = (const float*)d_in[2];  // (256,)          f32
    float* out = (float*)d_out;

    unsigned short* gw = (unsigned short*)d_ws;   // 245760 ushort = 491520 B

    prep_kernel<<<960, 256, 0, stream>>>(w, gw);
    pconv_mfma<<<dim3(128, 4, 8), 512, LDS_BYTES, stream>>>(gw, x, bb, out);
}